// Round 5
// baseline (779.835 us; speedup 1.0000x reference)
//
#include <hip/hip_runtime.h>

// B=4, S=2048, E=2048, H=16, D=128, full-head rope. f32 I/O, bf16 MFMA inside.
// Memory plan:
//   d_out: xb [0,32MiB) -> later ctx (same region); Qb [32,64MiB)
//   ws:    Kb [0,32), Vt [32,64), optional Wq_bf [64,88), Wo_bf [88,96)
//   GEMM2 -> f32 ws[0,64MiB), D2D copy to d_out.
// LDS tiles staged by global_load_lds are XOR-swizzled (chunk ^= row&7) to
// break the 16-way bank conflicts of unpadded 128B-stride rows (r6 counters).
// r9: attn paired q-tiles + async V + setprio. r11: swapped QK^T attn
// (mfma(K,Q) -> S^T, 2-shuffle softmax, b64 P stores) -> 735.7 us.
// r10 FAILED: invented 256x128/ring-3 schedule (8 MFMA/barrier) -> 412 us.
// r12: faithful m201-geometry port for both GEMMs: 256x256 tile, BK=64,
// 8 waves (2Mx4N, 128x64/wave), dbuf-2 LDS (128 KiB), 4 phases/K-tile each
// {stage 1 half-tile (2 gload_lds) || read-once ds_read frags || bar ||
// setprio(1) 16 MFMA setprio(0) || bar}, counted vmcnt(2) ONLY at tile
// boundary (never drain mid-loop). Staging runs 4-5 phases ahead; ph3 stages
// h0(t+2) into the CURRENT buffer's dead region (all its reads completed by
// ph2's closing barrier). Frag index patterns are r10-correctness-proven.

using frag_ab = __attribute__((ext_vector_type(8))) short;   // 8 bf16 = 4 VGPRs
using frag_cd = __attribute__((ext_vector_type(4))) float;   // 4 f32 acc
typedef __attribute__((ext_vector_type(2))) unsigned int uint2v;

__device__ __forceinline__ float b2f(unsigned short u) {
  union { unsigned int i; float f; } v; v.i = ((unsigned int)u) << 16; return v.f;
}
__device__ __forceinline__ unsigned short f2b(float f) {
  union { float f; unsigned int i; } v; v.f = f;
  unsigned int r = v.i + 0x7FFFu + ((v.i >> 16) & 1u);   // RNE
  return (unsigned short)(r >> 16);
}
__device__ __forceinline__ unsigned int pack2(float a, float b) {
  return (unsigned int)f2b(a) | ((unsigned int)f2b(b) << 16);
}
__device__ __forceinline__ void gload16(const unsigned short* g, unsigned short* l) {
  __builtin_amdgcn_global_load_lds(
      (const __attribute__((address_space(1))) unsigned int*)g,
      (__attribute__((address_space(3))) unsigned int*)l, 16, 0, 0);
}

// ---------------------------------------------------------------------------
__global__ __launch_bounds__(256)
void cvt_f32_bf16(const float* __restrict__ in, unsigned short* __restrict__ out) {
  long i = (long)(blockIdx.x * 256 + threadIdx.x) * 8;
  float4 a = *(const float4*)&in[i];
  float4 b = *(const float4*)&in[i + 4];
  uint4 p;
  p.x = pack2(a.x, a.y); p.y = pack2(a.z, a.w);
  p.z = pack2(b.x, b.y); p.w = pack2(b.z, b.w);
  *(uint4*)&out[i] = p;
}

// ---------------------------------------------------------------------------
// Staging helpers. stage_round512: 64 rows x 64 cols bf16 (8 KB), one gload16
// per thread at 512 threads (8 waves x 8 rows), chunk-XOR swizzle (ch ^= r&7).
// ---------------------------------------------------------------------------
__device__ __forceinline__ void stage_round512(const unsigned short* G, unsigned short* Ls,
                                               int row0, int k0, int rr0,
                                               int wave, int lane) {
  int r = rr0 + wave * 8 + (lane >> 3);
  int srcc = (lane & 7) ^ (r & 7);
  gload16(&G[(long)(row0 + r) * 2048 + k0 + srcc * 8], &Ls[(rr0 + wave * 8) * 64]);
}

// 256-thread variants (128^2 fallback kernels)
__device__ __forceinline__ void stage_a_async(const unsigned short* A, unsigned short* As,
                                              int row0, int k0, int wave, int lane, int ldk) {
#pragma unroll
  for (int i = 0; i < 4; i++) {
    int rbase = wave * 32 + i * 8;
    int r = rbase + (lane >> 3);
    int srcc = (lane & 7) ^ (r & 7);
    gload16(&A[(long)(row0 + r) * ldk + k0 + srcc * 8], &As[rbase * 64]);
  }
}
__device__ __forceinline__ void stage_b_cvt(const float* Bw, unsigned short* Bs,
                                            int row0, int k0, int tid) {
#pragma unroll
  for (int i = 0; i < 4; i++) {
    int c = tid + i * 256;                 // chunk id in [0,1024)
    int r = c >> 3, ch = c & 7;
    const float* src = &Bw[(long)(row0 + r) * 2048 + k0 + ch * 8];
    float4 v0 = *(const float4*)src;
    float4 v1 = *(const float4*)(src + 4);
    uint4 p;
    p.x = pack2(v0.x, v0.y); p.y = pack2(v0.z, v0.w);
    p.z = pack2(v1.x, v1.y); p.w = pack2(v1.z, v1.w);
    *(uint4*)&Bs[r * 64 + ((ch ^ (r & 7)) * 8)] = p;
  }
}

// ---------------------------------------------------------------------------
// r12 pipelined GEMM core macros (shared by qkv2/ctx2).
// Per K-tile t (buf c=t&1): 4 phases; stage h1..h3(t+1)->buf c^1 in ph0..2,
// h0(t+2)->buf c (dead rows 0-127 of A) in ph3; boundary vmcnt(2).
// LDA/LDB: frag at (row)*64 + ((ksub*4+quad)^(l16&7))*8.
// ---------------------------------------------------------------------------
#define LDA_(mi, ks) (*(const frag_ab*)&as[(wr * 128 + (mi) * 16 + l16) * 64 + ((((ks) * 4 + quad) ^ (l16 & 7)) * 8)])
#define LDB_(ni, ks) (*(const frag_ab*)&bs[(wc * 64  + (ni) * 16 + l16) * 64 + ((((ks) * 4 + quad) ^ (l16 & 7)) * 8)])

#define GEMM256_BODY(Aptr, Bptr)                                               \
  /* prologue: h0-h3(t=0)->buf0, h0(t=1)->buf1 */                              \
  stage_round512(Aptr, As_[0], row0A, 0, 0,   wave, lane);                     \
  stage_round512(Aptr, As_[0], row0A, 0, 64,  wave, lane);                     \
  stage_round512(Aptr, As_[0], row0A, 0, 128, wave, lane);                     \
  stage_round512(Aptr, As_[0], row0A, 0, 192, wave, lane);                     \
  stage_round512(Bptr, Bs_[0], row0B, 0, 0,   wave, lane);                     \
  stage_round512(Bptr, Bs_[0], row0B, 0, 64,  wave, lane);                     \
  stage_round512(Bptr, Bs_[0], row0B, 0, 128, wave, lane);                     \
  stage_round512(Bptr, Bs_[0], row0B, 0, 192, wave, lane);                     \
  stage_round512(Aptr, As_[1], row0A, 64, 0,  wave, lane);                     \
  stage_round512(Aptr, As_[1], row0A, 64, 64, wave, lane);                     \
  asm volatile("s_waitcnt vmcnt(2)" ::: "memory");                             \
  __builtin_amdgcn_s_barrier();                                                \
  for (int t = 0; t < 32; ++t) {                                               \
    const int c = t & 1;                                                       \
    const unsigned short* as = As_[c];                                         \
    const unsigned short* bs = Bs_[c];                                         \
    unsigned short* asN = As_[c ^ 1];                                          \
    unsigned short* bsN = Bs_[c ^ 1];                                          \
    unsigned short* asC = As_[c];                                              \
    const int k1 = (t + 1) * 64, k2 = (t + 2) * 64;                            \
    frag_ab aLo[2][4], aHi[2][4], bLo[2][2], bHi[2][2];                        \
    /* ---- ph0: stage h1(t+1)=A rows 128-255; read aLo,bLo; MFMA LoLo */      \
    if (t < 31) {                                                              \
      stage_round512(Aptr, asN, row0A, k1, 128, wave, lane);                   \
      stage_round512(Aptr, asN, row0A, k1, 192, wave, lane);                   \
    }                                                                          \
    _Pragma("unroll") for (int ks = 0; ks < 2; ks++) {                         \
      _Pragma("unroll") for (int mi = 0; mi < 4; mi++) aLo[ks][mi] = LDA_(mi, ks); \
      _Pragma("unroll") for (int ni = 0; ni < 2; ni++) bLo[ks][ni] = LDB_(ni, ks); \
    }                                                                          \
    __builtin_amdgcn_s_barrier();                                              \
    __builtin_amdgcn_s_setprio(1);                                             \
    _Pragma("unroll") for (int ks = 0; ks < 2; ks++)                           \
      _Pragma("unroll") for (int mi = 0; mi < 4; mi++)                         \
        _Pragma("unroll") for (int ni = 0; ni < 2; ni++)                       \
          acc[mi][ni] = __builtin_amdgcn_mfma_f32_16x16x32_bf16(aLo[ks][mi], bLo[ks][ni], acc[mi][ni], 0, 0, 0); \
    __builtin_amdgcn_s_setprio(0);                                             \
    __builtin_amdgcn_s_barrier();                                              \
    /* ---- ph1: stage h2(t+1)=B rows 0-127; read bHi; MFMA LoHi */            \
    if (t < 31) {                                                              \
      stage_round512(Bptr, bsN, row0B, k1, 0,  wave, lane);                    \
      stage_round512(Bptr, bsN, row0B, k1, 64, wave, lane);                    \
    }                                                                          \
    _Pragma("unroll") for (int ks = 0; ks < 2; ks++)                           \
      _Pragma("unroll") for (int ni = 0; ni < 2; ni++) bHi[ks][ni] = LDB_(2 + ni, ks); \
    __builtin_amdgcn_s_barrier();                                              \
    __builtin_amdgcn_s_setprio(1);                                             \
    _Pragma("unroll") for (int ks = 0; ks < 2; ks++)                           \
      _Pragma("unroll") for (int mi = 0; mi < 4; mi++)                         \
        _Pragma("unroll") for (int ni = 0; ni < 2; ni++)                       \
          acc[mi][2 + ni] = __builtin_amdgcn_mfma_f32_16x16x32_bf16(aLo[ks][mi], bHi[ks][ni], acc[mi][2 + ni], 0, 0, 0); \
    __builtin_amdgcn_s_setprio(0);                                             \
    __builtin_amdgcn_s_barrier();                                              \
    /* ---- ph2: stage h3(t+1)=B rows 128-255; read aHi; MFMA HiLo */          \
    if (t < 31) {                                                              \
      stage_round512(Bptr, bsN, row0B, k1, 128, wave, lane);                   \
      stage_round512(Bptr, bsN, row0B, k1, 192, wave, lane);                   \
    }                                                                          \
    _Pragma("unroll") for (int ks = 0; ks < 2; ks++)                           \
      _Pragma("unroll") for (int mi = 0; mi < 4; mi++) aHi[ks][mi] = LDA_(4 + mi, ks); \
    __builtin_amdgcn_s_barrier();                                              \
    __builtin_amdgcn_s_setprio(1);                                             \
    _Pragma("unroll") for (int ks = 0; ks < 2; ks++)                           \
      _Pragma("unroll") for (int mi = 0; mi < 4; mi++)                         \
        _Pragma("unroll") for (int ni = 0; ni < 2; ni++)                       \
          acc[4 + mi][ni] = __builtin_amdgcn_mfma_f32_16x16x32_bf16(aHi[ks][mi], bLo[ks][ni], acc[4 + mi][ni], 0, 0, 0); \
    __builtin_amdgcn_s_setprio(0);                                             \
    __builtin_amdgcn_s_barrier();                                              \
    /* ---- ph3: stage h0(t+2)=A rows 0-127 into CURRENT buf (dead); HiHi */   \
    if (t < 30) {                                                              \
      stage_round512(Aptr, asC, row0A, k2, 0,  wave, lane);                    \
      stage_round512(Aptr, asC, row0A, k2, 64, wave, lane);                    \
    }                                                                          \
    __builtin_amdgcn_s_barrier();                                              \
    __builtin_amdgcn_s_setprio(1);                                             \
    _Pragma("unroll") for (int ks = 0; ks < 2; ks++)                           \
      _Pragma("unroll") for (int mi = 0; mi < 4; mi++)                         \
        _Pragma("unroll") for (int ni = 0; ni < 2; ni++)                       \
          acc[4 + mi][2 + ni] = __builtin_amdgcn_mfma_f32_16x16x32_bf16(aHi[ks][mi], bHi[ks][ni], acc[4 + mi][2 + ni], 0, 0, 0); \
    __builtin_amdgcn_s_setprio(0);                                             \
    if (t < 30)       asm volatile("s_waitcnt vmcnt(2)" ::: "memory");         \
    else if (t == 30) asm volatile("s_waitcnt vmcnt(0)" ::: "memory");         \
    __builtin_amdgcn_s_barrier();                                              \
  }

// ---------------------------------------------------------------------------
// r12 GEMM1: qkv = xb @ Wq^T + bias -> Q,K (B,H,S,D), V^T (B,H,D,S)
// ---------------------------------------------------------------------------
__global__ __launch_bounds__(512, 2)
void gemm_qkv2(const unsigned short* __restrict__ A,    // xb (8192,2048) bf16
               const unsigned short* __restrict__ Bbf,  // wqkv_w bf16 (6144,2048)
               const float* __restrict__ bias,
               unsigned short* __restrict__ Qb,
               unsigned short* __restrict__ Kb,
               unsigned short* __restrict__ Vt) {
  __shared__ __align__(16) unsigned short As_[2][256 * 64];
  __shared__ __align__(16) unsigned short Bs_[2][256 * 64];
  const int tid  = threadIdx.x;
  const int wave = tid >> 6, lane = tid & 63;
  const int quad = lane >> 4, l16 = lane & 15;
  const int wr = wave >> 2, wc = wave & 3;       // 2M x 4N wave grid
  const int row0A = blockIdx.x * 256;
  const int row0B = blockIdx.y * 256;

  frag_cd acc[8][4];
#pragma unroll
  for (int i = 0; i < 8; i++)
#pragma unroll
    for (int j = 0; j < 4; j++) acc[i][j] = (frag_cd){0.f, 0.f, 0.f, 0.f};

  GEMM256_BODY(A, Bbf)

  // scatter epilogue (C/D layout: col=l16, row=quad*4+r; m89-verified)
#pragma unroll
  for (int ni = 0; ni < 4; ni++) {
    int col  = row0B + wc * 64 + ni * 16 + l16;
    int h    = col / 384;
    int rem  = col - h * 384;
    int slot = rem >> 7;
    int d    = rem & 127;
    float bv = bias[col];
#pragma unroll
    for (int mi = 0; mi < 8; mi++) {
#pragma unroll
      for (int r = 0; r < 4; r++) {
        int row = row0A + wr * 128 + mi * 16 + quad * 4 + r;
        int b = row >> 11, s = row & 2047;
        unsigned short val = f2b(acc[mi][ni][r] + bv);
        if (slot == 0)      Qb[((long)(b * 16 + h) * 2048 + s) * 128 + d] = val;
        else if (slot == 1) Kb[((long)(b * 16 + h) * 2048 + s) * 128 + d] = val;
        else                Vt[((long)(b * 16 + h) * 128 + d) * 2048 + s] = val;
      }
    }
  }
}

// ---------------------------------------------------------------------------
// r12 GEMM2: out(f32) = ctx(bf16) @ wo^T + wo_b
// ---------------------------------------------------------------------------
__global__ __launch_bounds__(512, 2)
void gemm_ctx2(const unsigned short* __restrict__ A,    // ctx (8192,2048) bf16
               const unsigned short* __restrict__ Bbf,  // wo_w bf16 (2048,2048)
               const float* __restrict__ bias,
               float* __restrict__ C) {
  __shared__ __align__(16) unsigned short As_[2][256 * 64];
  __shared__ __align__(16) unsigned short Bs_[2][256 * 64];
  const int tid  = threadIdx.x;
  const int wave = tid >> 6, lane = tid & 63;
  const int quad = lane >> 4, l16 = lane & 15;
  const int wr = wave >> 2, wc = wave & 3;
  const int row0A = blockIdx.x * 256;
  const int row0B = blockIdx.y * 256;

  frag_cd acc[8][4];
#pragma unroll
  for (int i = 0; i < 8; i++)
#pragma unroll
    for (int j = 0; j < 4; j++) acc[i][j] = (frag_cd){0.f, 0.f, 0.f, 0.f};

  GEMM256_BODY(A, Bbf)

#pragma unroll
  for (int ni = 0; ni < 4; ni++) {
    int col = row0B + wc * 64 + ni * 16 + l16;
    float bv = bias[col];
#pragma unroll
    for (int mi = 0; mi < 8; mi++) {
#pragma unroll
      for (int r = 0; r < 4; r++) {
        int row = row0A + wr * 128 + mi * 16 + quad * 4 + r;
        C[(long)row * 2048 + col] = acc[mi][ni][r] + bv;
      }
    }
  }
}
#undef LDA_
#undef LDB_

// ---------------------------------------------------------------------------
// Fallback GEMM1 (f32 weights, 128^2, 2-barrier): qkv = xb @ W^T + bias
// ---------------------------------------------------------------------------
__global__ __launch_bounds__(256)
void gemm_qkv(const unsigned short* __restrict__ A,
              const float* __restrict__ Bw,
              const float* __restrict__ bias,
              unsigned short* __restrict__ Qb,
              unsigned short* __restrict__ Kb,
              unsigned short* __restrict__ Vt) {
  __shared__ __align__(16) unsigned short As[128 * 64];
  __shared__ __align__(16) unsigned short Bs[128 * 64];
  const int tid  = threadIdx.x;
  const int wave = tid >> 6, lane = tid & 63;
  const int quad = lane >> 4, l16 = lane & 15;
  const int wm = (wave & 1) * 64, wn = (wave >> 1) * 64;
  const int row0A = blockIdx.x * 128;
  const int row0B = blockIdx.y * 128;

  frag_cd acc[4][4];
#pragma unroll
  for (int i = 0; i < 4; i++)
#pragma unroll
    for (int j = 0; j < 4; j++) acc[i][j] = (frag_cd){0.f, 0.f, 0.f, 0.f};

  for (int k0 = 0; k0 < 2048; k0 += 64) {
    stage_a_async(A, As, row0A, k0, wave, lane, 2048);
    stage_b_cvt(Bw, Bs, row0B, k0, tid);
    __syncthreads();
#pragma unroll
    for (int kk = 0; kk < 64; kk += 32) {
      frag_ab af[4], bf[4];
#pragma unroll
      for (int mi = 0; mi < 4; mi++) {
        int row = wm + mi * 16 + l16;
        af[mi] = *(const frag_ab*)&As[row * 64 + (((quad + (kk >> 3)) ^ (l16 & 7)) * 8)];
      }
#pragma unroll
      for (int ni = 0; ni < 4; ni++) {
        int row = wn + ni * 16 + l16;
        bf[ni] = *(const frag_ab*)&Bs[row * 64 + (((quad + (kk >> 3)) ^ (l16 & 7)) * 8)];
      }
#pragma unroll
      for (int mi = 0; mi < 4; mi++)
#pragma unroll
        for (int ni = 0; ni < 4; ni++)
          acc[mi][ni] = __builtin_amdgcn_mfma_f32_16x16x32_bf16(af[mi], bf[ni], acc[mi][ni], 0, 0, 0);
    }
    __syncthreads();
  }
#pragma unroll
  for (int ni = 0; ni < 4; ni++) {
    int col  = row0B + wn + ni * 16 + l16;
    int h    = col / 384;
    int rem  = col - h * 384;
    int slot = rem >> 7;
    int d    = rem & 127;
    float bv = bias[col];
#pragma unroll
    for (int mi = 0; mi < 4; mi++) {
#pragma unroll
      for (int r = 0; r < 4; r++) {
        int row = row0A + wm + mi * 16 + quad * 4 + r;
        int b = row >> 11, s = row & 2047;
        unsigned short val = f2b(acc[mi][ni][r] + bv);
        if (slot == 0)      Qb[((long)(b * 16 + h) * 2048 + s) * 128 + d] = val;
        else if (slot == 1) Kb[((long)(b * 16 + h) * 2048 + s) * 128 + d] = val;
        else                Vt[((long)(b * 16 + h) * 128 + d) * 2048 + s] = val;
      }
    }
  }
}

// ---------------------------------------------------------------------------
// rope in place; attention scale 1/sqrt(128) folded into Q here (free VALU).
// ---------------------------------------------------------------------------
__global__ __launch_bounds__(256)
void rope_inplace(unsigned short* __restrict__ Qb, unsigned short* __restrict__ Kb) {
  int wid  = blockIdx.x * 4 + (threadIdx.x >> 6);
  int j    = threadIdx.x & 63;
  int part = wid & 1;
  int s    = (wid >> 1) & 2047;
  int bh   = wid >> 12;
  unsigned short* buf = part ? Kb : Qb;
  long base = ((long)bh * 2048 + s) * 128;
  unsigned int pr = *(const unsigned int*)&buf[base + 2 * j];
  float x1 = b2f((unsigned short)(pr & 0xFFFFu));
  float x2 = b2f((unsigned short)(pr >> 16));
  float inv = powf(10000.0f, -(float)(2 * j) / 128.0f);
  float ang = (float)s * inv;
  float sn, cs;
  sincosf(ang, &sn, &cs);
  float sc = part ? 1.0f : 0.08838834764831845f;   // Q pre-scaled for attn
  cs *= sc; sn *= sc;
  buf[base + j]      = f2b(x1 * cs - x2 * sn);
  buf[base + 64 + j] = f2b(x1 * sn + x2 * cs);
}

// ---------------------------------------------------------------------------
// Causal flash attention (r11-proven). Q,K (B,H,S,D), Q pre-scaled; V^T.
// Paired q-tiles (qt,15-qt); swapped QK^T (mfma(K,Q) -> S^T); 2-shuffle
// softmax; b64 P stores; async swizzled K/V; setprio.
// ---------------------------------------------------------------------------
__global__ __launch_bounds__(256)
void attn_fwd(const unsigned short* __restrict__ Q,
              const unsigned short* __restrict__ K,
              const unsigned short* __restrict__ Vt,
              unsigned short* __restrict__ ctx) {
  __shared__ __align__(16) unsigned short Ks[64 * 128];   // 16-chunk XOR swizzle
  __shared__ __align__(16) unsigned short Vs[128 * 64];   // 8-chunk XOR swizzle
  __shared__ __align__(16) unsigned short Ps[4][32 * 64]; // per-wave P, swizzled
  const int bh = blockIdx.x;
  const int tid = threadIdx.x;
  const int wave = tid >> 6, lane = tid & 63;
  const int quad = lane >> 4, l16 = lane & 15;
  const long base  = (long)bh * 2048 * 128;
  const long vbase = (long)bh * 262144;
  const int b = bh >> 4, h = bh & 15;
  unsigned short* pw = &Ps[wave][0];

  for (int pass = 0; pass < 2; ++pass) {
    const int qt = pass ? (15 - blockIdx.y) : blockIdx.y;
    const int q0 = qt * 128 + wave * 32;

    frag_ab qf[2][4];
#pragma unroll
    for (int mi = 0; mi < 2; mi++)
#pragma unroll
      for (int ks = 0; ks < 4; ks++)
        qf[mi][ks] = *(const frag_ab*)&Q[base + (long)(q0 + mi * 16 + l16) * 128 + ks * 32 + quad * 8];

    frag_cd o[2][8];
#pragma unroll
    for (int mi = 0; mi < 2; mi++)
#pragma unroll
      for (int ni = 0; ni < 8; ni++) o[mi][ni] = (frag_cd){0.f, 0.f, 0.f, 0.f};
    float m_i[2] = {-1.0e30f, -1.0e30f};   // stats for q = l16 (dup across quads)
    float l_i[2] = {0.f, 0.f};

    const int kv_end = qt * 128 + 128;
    for (int kv0 = 0; kv0 < kv_end; kv0 += 64) {
      __syncthreads();
      // K: 64x128, 16-chunk XOR swizzle, async
#pragma unroll
      for (int i = 0; i < 4; i++) {
        int rbase = (wave * 4 + i) * 4;
        int r = rbase + (lane >> 4);
        int srcc = (lane & 15) ^ (r & 15);
        gload16(&K[base + (long)(kv0 + r) * 128 + srcc * 8], &Ks[rbase * 128]);
      }
      // V^T: 128x64, 8-chunk XOR swizzle, async
#pragma unroll
      for (int i = 0; i < 4; i++) {
        int rbase = wave * 32 + i * 8;
        int r = rbase + (lane >> 3);
        int srcc = (lane & 7) ^ (r & 7);
        gload16(&Vt[vbase + (long)r * 2048 + kv0 + srcc * 8], &Vs[rbase * 64]);
      }
      __syncthreads();

      if (kv0 <= q0 + 31) {                 // else: fully masked for this wave
        // S^T = K @ Q^T : p[mi][kt][r] = S[q=l16][kv=kt*16+quad*4+r]
        float p[2][4][4];
        __builtin_amdgcn_s_setprio(1);
#pragma unroll
        for (int kt = 0; kt < 4; kt++) {
          frag_ab kf[4];
          int row = kt * 16 + l16;
#pragma unroll
          for (int ks = 0; ks < 4; ks++)
            kf[ks] = *(const frag_ab*)&Ks[row * 128 + (((ks * 4 + quad) ^ (row & 15)) * 8)];
#pragma unroll
          for (int mi = 0; mi < 2; mi++) {
            frag_cd acc = (frag_cd){0.f, 0.f, 0.f, 0.f};
#pragma unroll
            for (int ks = 0; ks < 4; ks++)
              acc = __builtin_amdgcn_mfma_f32_16x16x32_bf16(kf[ks], qf[mi][ks], acc, 0, 0, 0);
#pragma unroll
            for (int r = 0; r < 4; r++) p[mi][kt][r] = acc[r];
          }
        }
        __builtin_amdgcn_s_setprio(0);

        if (kv0 + 63 > q0) {               // diagonal tiles: apply causal mask
#pragma unroll
          for (int mi = 0; mi < 2; mi++) {
            int qg = q0 + mi * 16 + l16;
#pragma unroll
            for (int kt = 0; kt < 4; kt++)
#pragma unroll
              for (int r = 0; r < 4; r++) {
                int kvg = kv0 + kt * 16 + quad * 4 + r;
                if (kvg > qg) p[mi][kt][r] = -10000.0f;
              }
          }
        }

        // online softmax: stats per q=l16, replicated across quads
        float alpha[2];
#pragma unroll
        for (int mi = 0; mi < 2; mi++) {
          float mx = -1.0e30f;
#pragma unroll
          for (int kt = 0; kt < 4; kt++)
            mx = fmaxf(mx, fmaxf(fmaxf(p[mi][kt][0], p[mi][kt][1]),
                                 fmaxf(p[mi][kt][2], p[mi][kt][3])));
          mx = fmaxf(mx, __shfl_xor(mx, 16, 64));
          mx = fmaxf(mx, __shfl_xor(mx, 32, 64));
          float mnew = fmaxf(m_i[mi], mx);
          alpha[mi] = __expf(m_i[mi] - mnew);
          m_i[mi] = mnew;
          float rs = 0.f;
#pragma unroll
          for (int kt = 0; kt < 4; kt++)
#pragma unroll
            for (int r = 0; r < 4; r++) {
              float e = __expf(p[mi][kt][r] - mnew);
              p[mi][kt][r] = e;
              rs += e;
            }
          rs += __shfl_xor(rs, 16, 64);
          rs += __shfl_xor(rs, 32, 64);
          l_i[mi] = l_i[mi] * alpha[mi] + rs;
        }

        // rescale O (alpha at q=l16 lanes; o rows are q=quad*4+r)
        if (!(__all(alpha[0] == 1.0f) && __all(alpha[1] == 1.0f))) {
#pragma unroll
          for (int mi = 0; mi < 2; mi++) {
            float ar[4];
#pragma unroll
            for (int r = 0; r < 4; r++) ar[r] = __shfl(alpha[mi], quad * 4 + r, 64);
#pragma unroll
            for (int ni = 0; ni < 8; ni++)
#pragma unroll
              for (int r = 0; r < 4; r++) o[mi][ni][r] *= ar[r];
          }
        }

        // P -> LDS: b64 packed, chunk-XOR swizzle (row = mi*16+l16 = q)
#pragma unroll
        for (int mi = 0; mi < 2; mi++) {
          int row = mi * 16 + l16;
#pragma unroll
          for (int kt = 0; kt < 4; kt++) {
            unsigned int u0 = pack2(p[mi][kt][0], p[mi][kt][1]);
            unsigned int u1 = pack2(p[mi][kt][2], p[mi][kt][3]);
            int ch = kt * 2 + (quad >> 1);
            int addr = row * 64 + ((ch ^ (l16 & 7)) * 8) + (quad & 1) * 4;
            *(uint2v*)&pw[addr] = (uint2v){u0, u1};
          }
        }

        // O += P @ V  (pf: A-operand rows q=l16; vf: B-operand rows d=l16)
        frag_ab pf[2][2];
#pragma unroll
        for (int mi = 0; mi < 2; mi++)
#pragma unroll
          for (int ks = 0; ks < 2; ks++)
            pf[mi][ks] = *(const frag_ab*)&pw[(mi * 16 + l16) * 64 +
                                              (((ks * 4 + quad) ^ (l16 & 7)) * 8)];
        __builtin_amdgcn_s_setprio(1);
#pragma unroll
        for (int ni = 0; ni < 8; ni++) {
          int vrow = ni * 16 + l16;
          frag_ab vf0 = *(const frag_ab*)&Vs[vrow * 64 + ((quad ^ (l16 & 7)) * 8)];
          frag_ab vf1 = *(const frag_ab*)&Vs[vrow * 64 + (((quad + 4) ^ (l16 & 7)) * 8)];
#pragma unroll
          for (int mi = 0; mi < 2; mi++) {
            o[mi][ni] = __builtin_amdgcn_mfma_f32_16x16x32_bf16(pf[mi][0], vf0, o[mi][ni], 0, 0, 0);
            o[mi][ni] = __builtin_amdgcn_mfma_f32_16x16x32_bf16(pf[mi][1], vf1, o[mi][ni], 0, 0, 0);
          }
        }
        __builtin_amdgcn_s_setprio(0);
      }
    }

    // ctx row-major (B,S,E); 1/l broadcast from q=l16 lanes to o-rows
#pragma unroll
    for (int mi = 0; mi < 2; mi++) {
      float rl = 1.0f / fmaxf(l_i[mi], 1.0e-20f);
#pragma unroll
      for (int r = 0; r < 4; r++) {
        float inv = __shfl(rl, quad * 4 + r, 64);
        int s = q0 + mi * 16 + quad * 4 + r;
        long rowb = ((long)b * 2048 + s) * 2048 + h * 128;
#pragma unroll
        for (int ni = 0; ni < 8; ni++)
          ctx[rowb + ni * 16 + l16] = f2b(o[mi][ni][r] * inv);
      }
    }
  }
}

// ---------------------------------------------------------------------------
// Fallback GEMM2 (f32 weights, 128^2): out(f32) = ctx @ wo^T + wo_b
// ---------------------------------------------------------------------------
__global__ __launch_bounds__(256)
void gemm_ctx(const unsigned short* __restrict__ A,
              const float* __restrict__ Bw,
              const float* __restrict__ bias,
              float* __restrict__ C) {
  __shared__ __align__(16) unsigned short As[128 * 64];
  __shared__ __align__(16) unsigned short Bs[128 * 64];
  const int tid  = threadIdx.x;
  const int wave = tid >> 6, lane = tid & 63;
  const int quad = lane >> 4, l16 = lane & 15;
  const int wm = (wave & 1) * 64, wn = (wave >> 1) * 64;
  const int row0A = blockIdx.x * 128;
  const int row0B = blockIdx.y * 128;

  frag_cd acc[4][4];
#pragma unroll
  for (int i = 0; i < 4; i++)
#pragma unroll
    for (int j = 0; j < 4; j++) acc[i][j] = (frag_cd){0.f, 0.f, 0.f, 0.f};

  for (int k0 = 0; k0 < 2048; k0 += 64) {
    stage_a_async(A, As, row0A, k0, wave, lane, 2048);
    stage_b_cvt(Bw, Bs, row0B, k0, tid);
    __syncthreads();
#pragma unroll
    for (int kk = 0; kk < 64; kk += 32) {
      frag_ab af[4], bf[4];
#pragma unroll
      for (int mi = 0; mi < 4; mi++) {
        int row = wm + mi * 16 + l16;
        af[mi] = *(const frag_ab*)&As[row * 64 + (((quad + (kk >> 3)) ^ (l16 & 7)) * 8)];
      }
#pragma unroll
      for (int ni = 0; ni < 4; ni++) {
        int row = wn + ni * 16 + l16;
        bf[ni] = *(const frag_ab*)&Bs[row * 64 + (((quad + (kk >> 3)) ^ (l16 & 7)) * 8)];
      }
#pragma unroll
      for (int mi = 0; mi < 4; mi++)
#pragma unroll
        for (int ni = 0; ni < 4; ni++)
          acc[mi][ni] = __builtin_amdgcn_mfma_f32_16x16x32_bf16(af[mi], bf[ni], acc[mi][ni], 0, 0, 0);
    }
    __syncthreads();
  }
#pragma unroll
  for (int ni = 0; ni < 4; ni++) {
    int col = row0B + wn + ni * 16 + l16;
    float bv = bias[col];
#pragma unroll
    for (int mi = 0; mi < 4; mi++) {
#pragma unroll
      for (int r = 0; r < 4; r++) {
        int row = row0A + wm + mi * 16 + quad * 4 + r;
        C[(long)row * 2048 + col] = acc[mi][ni][r] + bv;
      }
    }
  }
}

// ---------------------------------------------------------------------------
extern "C" void kernel_launch(void* const* d_in, const int* in_sizes, int n_in,
                              void* d_out, int out_size, void* d_ws, size_t ws_size,
                              hipStream_t stream) {
  const float* x      = (const float*)d_in[0];
  const float* wqkv_w = (const float*)d_in[1];
  const float* wqkv_b = (const float*)d_in[2];
  const float* wo_w   = (const float*)d_in[3];
  const float* wo_b   = (const float*)d_in[4];

  unsigned short* xb  = (unsigned short*)d_out;              // [0,32MiB)
  unsigned short* Qb  = (unsigned short*)d_out + 16777216;   // [32,64MiB)
  unsigned short* Kb  = (unsigned short*)d_ws;               // ws [0,32MiB)
  unsigned short* Vt  = (unsigned short*)d_ws + 16777216;    // ws [32,64MiB)
  unsigned short* ctx = (unsigned short*)d_out;              // over xb (dead)
  float* outf = (float*)d_ws;                                // ws [0,64MiB)

  const bool big = ws_size >= 100663296UL;  // 96 MiB: room for bf16 weights
  unsigned short* Wq = big ? (unsigned short*)d_ws + 33554432 : nullptr; // [64,88MiB)
  unsigned short* Wo = big ? (unsigned short*)d_ws + 46137344 : nullptr; // [88,96MiB)

  // 0) conversions
  cvt_f32_bf16<<<8192, 256, 0, stream>>>(x, xb);
  if (big) {
    cvt_f32_bf16<<<6144, 256, 0, stream>>>(wqkv_w, Wq);
    cvt_f32_bf16<<<2048, 256, 0, stream>>>(wo_w, Wo);
  }
  // 1) QKV projection -> Q,K (bhsd), V^T (bhds)
  if (big) gemm_qkv2<<<dim3(32, 24), 512, 0, stream>>>(xb, Wq, wqkv_b, Qb, Kb, Vt);
  else     gemm_qkv<<<dim3(64, 48), 256, 0, stream>>>(xb, wqkv_w, wqkv_b, Qb, Kb, Vt);
  // 2) rope in place (folds attn scale into Q)
  rope_inplace<<<65536, 256, 0, stream>>>(Qb, Kb);
  // 3) flash attention, paired q-tiles, swapped QK^T -> ctx (B,S,E) bf16
  attn_fwd<<<dim3(64, 8), 256, 0, stream>>>(Qb, Kb, Vt, ctx);
  // 4) output projection -> f32 ws, copy back
  if (big) gemm_ctx2<<<dim3(32, 8), 512, 0, stream>>>(ctx, Wo, wo_b, outf);
  else     gemm_ctx<<<dim3(64, 16), 256, 0, stream>>>(ctx, wo_w, wo_b, outf);
  hipMemcpyAsync(d_out, outf, 67108864UL, hipMemcpyDeviceToDevice, stream);
}

// Round 6
// 712.292 us; speedup vs baseline: 1.0948x; 1.0948x over previous
//
#include <hip/hip_runtime.h>

// B=4, S=2048, E=2048, H=16, D=128, full-head rope. f32 I/O, bf16 MFMA inside.
// Memory plan:
//   d_out: xb [0,32MiB) -> rope table (1MiB, xb dead) -> ctx; Qb [32,64MiB)
//   ws:    Kb [0,32), Vt [32,64), optional Wq_bf [64,88), Wo_bf [88,96)
//   GEMM2 -> f32 ws[0,64MiB), D2D copy to d_out.
// LDS tiles staged by global_load_lds are XOR-swizzled (chunk ^= row&7) to
// break the 16-way bank conflicts of unpadded 128B-stride rows (r6 counters).
// r9: attn paired q-tiles + async V + setprio. r11: swapped QK^T attn
// (mfma(K,Q) -> S^T, 2-shuffle softmax, b64 P stores) -> 735.7 us.
// r10/r12 FAILED: two 8-phase/counted-vmcnt GEMM ports both regressed
// (412 / 299 us vs 273 us for the plain 128^2 2-barrier loop). Lane closed;
// GEMMs stay 128^2.
// r13: (a) attn K/V LDS double-buffer: issue tile t+1's global_load_lds at
// the top of tile t's compute, drain at the single end-of-tile barrier
// (T14 issue-early/wait-late; 1 barrier/tile instead of 2, full overlap).
// 80KB LDS = exactly 2 blocks/CU = the 512-block grid. (b) rope cos/sin
// f32 table (2048x64) built into the dead xb region -> rope is memory-bound.

using frag_ab = __attribute__((ext_vector_type(8))) short;   // 8 bf16 = 4 VGPRs
using frag_cd = __attribute__((ext_vector_type(4))) float;   // 4 f32 acc
typedef __attribute__((ext_vector_type(2))) unsigned int uint2v;

__device__ __forceinline__ float b2f(unsigned short u) {
  union { unsigned int i; float f; } v; v.i = ((unsigned int)u) << 16; return v.f;
}
__device__ __forceinline__ unsigned short f2b(float f) {
  union { float f; unsigned int i; } v; v.f = f;
  unsigned int r = v.i + 0x7FFFu + ((v.i >> 16) & 1u);   // RNE
  return (unsigned short)(r >> 16);
}
__device__ __forceinline__ unsigned int pack2(float a, float b) {
  return (unsigned int)f2b(a) | ((unsigned int)f2b(b) << 16);
}
__device__ __forceinline__ void gload16(const unsigned short* g, unsigned short* l) {
  __builtin_amdgcn_global_load_lds(
      (const __attribute__((address_space(1))) unsigned int*)g,
      (__attribute__((address_space(3))) unsigned int*)l, 16, 0, 0);
}

// ---------------------------------------------------------------------------
__global__ __launch_bounds__(256)
void cvt_f32_bf16(const float* __restrict__ in, unsigned short* __restrict__ out) {
  long i = (long)(blockIdx.x * 256 + threadIdx.x) * 8;
  float4 a = *(const float4*)&in[i];
  float4 b = *(const float4*)&in[i + 4];
  uint4 p;
  p.x = pack2(a.x, a.y); p.y = pack2(a.z, a.w);
  p.z = pack2(b.x, b.y); p.w = pack2(b.z, b.w);
  *(uint4*)&out[i] = p;
}

// ---------------------------------------------------------------------------
// Shared GEMM staging (128x64 bf16 tile, XOR-swizzled chunks).
// A always bf16 via global_load_lds. B: bf16 async if Bbf, else f32 inline cvt.
// Fragment read: phys chunk = (quad + kk/8) ^ (l16 & 7).
// ---------------------------------------------------------------------------
__device__ __forceinline__ void stage_a_async(const unsigned short* A, unsigned short* As,
                                              int row0, int k0, int wave, int lane, int ldk) {
#pragma unroll
  for (int i = 0; i < 4; i++) {
    int rbase = wave * 32 + i * 8;
    int r = rbase + (lane >> 3);
    int srcc = (lane & 7) ^ (r & 7);
    gload16(&A[(long)(row0 + r) * ldk + k0 + srcc * 8], &As[rbase * 64]);
  }
}
__device__ __forceinline__ void stage_b_cvt(const float* Bw, unsigned short* Bs,
                                            int row0, int k0, int tid) {
#pragma unroll
  for (int i = 0; i < 4; i++) {
    int c = tid + i * 256;                 // chunk id in [0,1024)
    int r = c >> 3, ch = c & 7;
    const float* src = &Bw[(long)(row0 + r) * 2048 + k0 + ch * 8];
    float4 v0 = *(const float4*)src;
    float4 v1 = *(const float4*)(src + 4);
    uint4 p;
    p.x = pack2(v0.x, v0.y); p.y = pack2(v0.z, v0.w);
    p.z = pack2(v1.x, v1.y); p.w = pack2(v1.z, v1.w);
    *(uint4*)&Bs[r * 64 + ((ch ^ (r & 7)) * 8)] = p;
  }
}

// ---------------------------------------------------------------------------
// GEMM1: qkv = xb @ W^T + bias -> Q (B,H,S,D), K (B,H,S,D), V^T (B,H,D,S)
// ---------------------------------------------------------------------------
__global__ __launch_bounds__(256)
void gemm_qkv(const unsigned short* __restrict__ A,    // xb (8192,2048) bf16
              const float* __restrict__ Bw,            // wqkv_w f32
              const unsigned short* __restrict__ Bbf,  // wqkv_w bf16 or null
              const float* __restrict__ bias,
              unsigned short* __restrict__ Qb,
              unsigned short* __restrict__ Kb,
              unsigned short* __restrict__ Vt) {
  __shared__ __align__(16) unsigned short As[128 * 64];
  __shared__ __align__(16) unsigned short Bs[128 * 64];
  const int tid  = threadIdx.x;
  const int wave = tid >> 6, lane = tid & 63;
  const int quad = lane >> 4, l16 = lane & 15;
  const int wm = (wave & 1) * 64, wn = (wave >> 1) * 64;
  const int row0A = blockIdx.x * 128;
  const int row0B = blockIdx.y * 128;

  frag_cd acc[4][4];
#pragma unroll
  for (int i = 0; i < 4; i++)
#pragma unroll
    for (int j = 0; j < 4; j++) acc[i][j] = (frag_cd){0.f, 0.f, 0.f, 0.f};

  for (int k0 = 0; k0 < 2048; k0 += 64) {
    stage_a_async(A, As, row0A, k0, wave, lane, 2048);
    if (Bbf) stage_a_async(Bbf, Bs, row0B, k0, wave, lane, 2048);
    else     stage_b_cvt(Bw, Bs, row0B, k0, tid);
    __syncthreads();
#pragma unroll
    for (int kk = 0; kk < 64; kk += 32) {
      frag_ab af[4], bf[4];
#pragma unroll
      for (int mi = 0; mi < 4; mi++) {
        int row = wm + mi * 16 + l16;
        af[mi] = *(const frag_ab*)&As[row * 64 + (((quad + (kk >> 3)) ^ (l16 & 7)) * 8)];
      }
#pragma unroll
      for (int ni = 0; ni < 4; ni++) {
        int row = wn + ni * 16 + l16;
        bf[ni] = *(const frag_ab*)&Bs[row * 64 + (((quad + (kk >> 3)) ^ (l16 & 7)) * 8)];
      }
#pragma unroll
      for (int mi = 0; mi < 4; mi++)
#pragma unroll
        for (int ni = 0; ni < 4; ni++)
          acc[mi][ni] = __builtin_amdgcn_mfma_f32_16x16x32_bf16(af[mi], bf[ni], acc[mi][ni], 0, 0, 0);
    }
    __syncthreads();
  }
  // scatter epilogue (C/D layout: col=l16, row=quad*4+r; m89-verified)
#pragma unroll
  for (int ni = 0; ni < 4; ni++) {
    int col  = row0B + wn + ni * 16 + l16;
    int h    = col / 384;
    int rem  = col - h * 384;
    int slot = rem >> 7;
    int d    = rem & 127;
    float bv = bias[col];
#pragma unroll
    for (int mi = 0; mi < 4; mi++) {
#pragma unroll
      for (int r = 0; r < 4; r++) {
        int row = row0A + wm + mi * 16 + quad * 4 + r;
        int b = row >> 11, s = row & 2047;
        unsigned short val = f2b(acc[mi][ni][r] + bv);
        if (slot == 0)      Qb[((long)(b * 16 + h) * 2048 + s) * 128 + d] = val;
        else if (slot == 1) Kb[((long)(b * 16 + h) * 2048 + s) * 128 + d] = val;
        else                Vt[((long)(b * 16 + h) * 128 + d) * 2048 + s] = val;
      }
    }
  }
}

// ---------------------------------------------------------------------------
// rope table: tab[s][j] = (cos, sin) of s * 10000^(-2j/128); 2048x64 float2.
// ---------------------------------------------------------------------------
__global__ __launch_bounds__(256)
void rope_tab(float2* __restrict__ tab) {
  int i = blockIdx.x * 256 + threadIdx.x;   // 131072
  int s = i >> 6, j = i & 63;
  float inv = powf(10000.0f, -(float)(2 * j) / 128.0f);
  float ang = (float)s * inv;
  float sn, cs;
  sincosf(ang, &sn, &cs);
  tab[i] = make_float2(cs, sn);
}

// ---------------------------------------------------------------------------
// rope in place from table; attention scale 1/sqrt(128) folded into Q.
// ---------------------------------------------------------------------------
__global__ __launch_bounds__(256)
void rope_inplace(unsigned short* __restrict__ Qb, unsigned short* __restrict__ Kb,
                  const float2* __restrict__ tab) {
  int wid  = blockIdx.x * 4 + (threadIdx.x >> 6);
  int j    = threadIdx.x & 63;
  int part = wid & 1;
  int s    = (wid >> 1) & 2047;
  int bh   = wid >> 12;
  unsigned short* buf = part ? Kb : Qb;
  long base = ((long)bh * 2048 + s) * 128;
  unsigned int pr = *(const unsigned int*)&buf[base + 2 * j];
  float x1 = b2f((unsigned short)(pr & 0xFFFFu));
  float x2 = b2f((unsigned short)(pr >> 16));
  float2 t = tab[s * 64 + j];
  float sc = part ? 1.0f : 0.08838834764831845f;   // Q pre-scaled for attn
  float cs = t.x * sc, sn = t.y * sc;
  buf[base + j]      = f2b(x1 * cs - x2 * sn);
  buf[base + 64 + j] = f2b(x1 * sn + x2 * cs);
}

// ---------------------------------------------------------------------------
// Causal flash attention. Q,K (B,H,S,D), Q pre-scaled; V^T (B,H,D,S).
// ctx -> (B,S,E) bf16.
// r11-proven compute: swapped QK^T (mfma(K,Q) -> S^T), 2-shuffle softmax,
// b64 P stores; paired q-tiles (qt, 15-qt) -> 512 blocks = 2/CU.
// r13: K/V LDS double-buffer. Per tile t: issue t+1's global_load_lds into
// buf[(t+1)&1] FIRST, then compute on buf[t&1], then one __syncthreads
// (drains vmcnt + barrier). Loads overlap the whole compute phase.
// Race-free: buffer written at t was last read at t-1 (barrier between);
// nt is even so the cross-pass prologue write to buf0 is barrier-separated.
// ---------------------------------------------------------------------------
__device__ __forceinline__ void attn_stage(const unsigned short* __restrict__ K,
                                           const unsigned short* __restrict__ Vt,
                                           long base, long vbase, int kv0,
                                           unsigned short* Kbuf, unsigned short* Vbuf,
                                           int wave, int lane) {
  // K: 64x128, 16-chunk XOR swizzle
#pragma unroll
  for (int i = 0; i < 4; i++) {
    int rbase = (wave * 4 + i) * 4;
    int r = rbase + (lane >> 4);
    int srcc = (lane & 15) ^ (r & 15);
    gload16(&K[base + (long)(kv0 + r) * 128 + srcc * 8], &Kbuf[rbase * 128]);
  }
  // V^T: 128x64, 8-chunk XOR swizzle
#pragma unroll
  for (int i = 0; i < 4; i++) {
    int rbase = wave * 32 + i * 8;
    int r = rbase + (lane >> 3);
    int srcc = (lane & 7) ^ (r & 7);
    gload16(&Vt[vbase + (long)r * 2048 + kv0 + srcc * 8], &Vbuf[rbase * 64]);
  }
}

__global__ __launch_bounds__(256)
void attn_fwd(const unsigned short* __restrict__ Q,
              const unsigned short* __restrict__ K,
              const unsigned short* __restrict__ Vt,
              unsigned short* __restrict__ ctx) {
  __shared__ __align__(16) unsigned short Ks[2][64 * 128];  // 32 KB
  __shared__ __align__(16) unsigned short Vs[2][128 * 64];  // 32 KB
  __shared__ __align__(16) unsigned short Ps[4][32 * 64];   // 16 KB, per-wave
  const int bh = blockIdx.x;
  const int tid = threadIdx.x;
  const int wave = tid >> 6, lane = tid & 63;
  const int quad = lane >> 4, l16 = lane & 15;
  const long base  = (long)bh * 2048 * 128;
  const long vbase = (long)bh * 262144;
  const int b = bh >> 4, h = bh & 15;
  unsigned short* pw = &Ps[wave][0];

  for (int pass = 0; pass < 2; ++pass) {
    const int qt = pass ? (15 - blockIdx.y) : blockIdx.y;
    const int q0 = qt * 128 + wave * 32;

    frag_ab qf[2][4];
#pragma unroll
    for (int mi = 0; mi < 2; mi++)
#pragma unroll
      for (int ks = 0; ks < 4; ks++)
        qf[mi][ks] = *(const frag_ab*)&Q[base + (long)(q0 + mi * 16 + l16) * 128 + ks * 32 + quad * 8];

    frag_cd o[2][8];
#pragma unroll
    for (int mi = 0; mi < 2; mi++)
#pragma unroll
      for (int ni = 0; ni < 8; ni++) o[mi][ni] = (frag_cd){0.f, 0.f, 0.f, 0.f};
    float m_i[2] = {-1.0e30f, -1.0e30f};   // stats for q = l16 (dup across quads)
    float l_i[2] = {0.f, 0.f};

    const int nt = qt * 2 + 2;             // kv tiles (even)
    attn_stage(K, Vt, base, vbase, 0, Ks[0], Vs[0], wave, lane);
    __syncthreads();

    for (int t = 0; t < nt; ++t) {
      const int kv0 = t * 64;
      const int c = t & 1;
      if (t + 1 < nt)                      // issue next tile NOW (overlaps compute)
        attn_stage(K, Vt, base, vbase, kv0 + 64, Ks[c ^ 1], Vs[c ^ 1], wave, lane);

      if (kv0 <= q0 + 31) {                // else: fully masked for this wave
        const unsigned short* ks_ = Ks[c];
        const unsigned short* vs_ = Vs[c];
        // S^T = K @ Q^T : p[mi][kt][r] = S[q=l16][kv=kt*16+quad*4+r]
        float p[2][4][4];
        __builtin_amdgcn_s_setprio(1);
#pragma unroll
        for (int kt = 0; kt < 4; kt++) {
          frag_ab kf[4];
          int row = kt * 16 + l16;
#pragma unroll
          for (int ks = 0; ks < 4; ks++)
            kf[ks] = *(const frag_ab*)&ks_[row * 128 + (((ks * 4 + quad) ^ (row & 15)) * 8)];
#pragma unroll
          for (int mi = 0; mi < 2; mi++) {
            frag_cd acc = (frag_cd){0.f, 0.f, 0.f, 0.f};
#pragma unroll
            for (int ks = 0; ks < 4; ks++)
              acc = __builtin_amdgcn_mfma_f32_16x16x32_bf16(kf[ks], qf[mi][ks], acc, 0, 0, 0);
#pragma unroll
            for (int r = 0; r < 4; r++) p[mi][kt][r] = acc[r];
          }
        }
        __builtin_amdgcn_s_setprio(0);

        if (kv0 + 63 > q0) {               // diagonal tiles: apply causal mask
#pragma unroll
          for (int mi = 0; mi < 2; mi++) {
            int qg = q0 + mi * 16 + l16;
#pragma unroll
            for (int kt = 0; kt < 4; kt++)
#pragma unroll
              for (int r = 0; r < 4; r++) {
                int kvg = kv0 + kt * 16 + quad * 4 + r;
                if (kvg > qg) p[mi][kt][r] = -10000.0f;
              }
          }
        }

        // online softmax: stats per q=l16, replicated across quads
        float alpha[2];
#pragma unroll
        for (int mi = 0; mi < 2; mi++) {
          float mx = -1.0e30f;
#pragma unroll
          for (int kt = 0; kt < 4; kt++)
            mx = fmaxf(mx, fmaxf(fmaxf(p[mi][kt][0], p[mi][kt][1]),
                                 fmaxf(p[mi][kt][2], p[mi][kt][3])));
          mx = fmaxf(mx, __shfl_xor(mx, 16, 64));
          mx = fmaxf(mx, __shfl_xor(mx, 32, 64));
          float mnew = fmaxf(m_i[mi], mx);
          alpha[mi] = __expf(m_i[mi] - mnew);
          m_i[mi] = mnew;
          float rs = 0.f;
#pragma unroll
          for (int kt = 0; kt < 4; kt++)
#pragma unroll
            for (int r = 0; r < 4; r++) {
              float e = __expf(p[mi][kt][r] - mnew);
              p[mi][kt][r] = e;
              rs += e;
            }
          rs += __shfl_xor(rs, 16, 64);
          rs += __shfl_xor(rs, 32, 64);
          l_i[mi] = l_i[mi] * alpha[mi] + rs;
        }

        // rescale O (alpha at q=l16 lanes; o rows are q=quad*4+r)
        if (!(__all(alpha[0] == 1.0f) && __all(alpha[1] == 1.0f))) {
#pragma unroll
          for (int mi = 0; mi < 2; mi++) {
            float ar[4];
#pragma unroll
            for (int r = 0; r < 4; r++) ar[r] = __shfl(alpha[mi], quad * 4 + r, 64);
#pragma unroll
            for (int ni = 0; ni < 8; ni++)
#pragma unroll
              for (int r = 0; r < 4; r++) o[mi][ni][r] *= ar[r];
          }
        }

        // P -> LDS: b64 packed, chunk-XOR swizzle (row = mi*16+l16 = q)
#pragma unroll
        for (int mi = 0; mi < 2; mi++) {
          int row = mi * 16 + l16;
#pragma unroll
          for (int kt = 0; kt < 4; kt++) {
            unsigned int u0 = pack2(p[mi][kt][0], p[mi][kt][1]);
            unsigned int u1 = pack2(p[mi][kt][2], p[mi][kt][3]);
            int ch = kt * 2 + (quad >> 1);
            int addr = row * 64 + ((ch ^ (l16 & 7)) * 8) + (quad & 1) * 4;
            *(uint2v*)&pw[addr] = (uint2v){u0, u1};
          }
        }

        // O += P @ V  (pf: A-operand rows q=l16; vf: B-operand rows d=l16)
        frag_ab pf[2][2];
#pragma unroll
        for (int mi = 0; mi < 2; mi++)
#pragma unroll
          for (int ks = 0; ks < 2; ks++)
            pf[mi][ks] = *(const frag_ab*)&pw[(mi * 16 + l16) * 64 +
                                              (((ks * 4 + quad) ^ (l16 & 7)) * 8)];
        __builtin_amdgcn_s_setprio(1);
#pragma unroll
        for (int ni = 0; ni < 8; ni++) {
          int vrow = ni * 16 + l16;
          frag_ab vf0 = *(const frag_ab*)&vs_[vrow * 64 + ((quad ^ (l16 & 7)) * 8)];
          frag_ab vf1 = *(const frag_ab*)&vs_[vrow * 64 + (((quad + 4) ^ (l16 & 7)) * 8)];
#pragma unroll
          for (int mi = 0; mi < 2; mi++) {
            o[mi][ni] = __builtin_amdgcn_mfma_f32_16x16x32_bf16(pf[mi][0], vf0, o[mi][ni], 0, 0, 0);
            o[mi][ni] = __builtin_amdgcn_mfma_f32_16x16x32_bf16(pf[mi][1], vf1, o[mi][ni], 0, 0, 0);
          }
        }
        __builtin_amdgcn_s_setprio(0);
      }
      __syncthreads();                     // drains next-tile loads + barrier
    }

    // ctx row-major (B,S,E); 1/l broadcast from q=l16 lanes to o-rows
#pragma unroll
    for (int mi = 0; mi < 2; mi++) {
      float rl = 1.0f / fmaxf(l_i[mi], 1.0e-20f);
#pragma unroll
      for (int r = 0; r < 4; r++) {
        float inv = __shfl(rl, quad * 4 + r, 64);
        int s = q0 + mi * 16 + quad * 4 + r;
        long rowb = ((long)b * 2048 + s) * 2048 + h * 128;
#pragma unroll
        for (int ni = 0; ni < 8; ni++)
          ctx[rowb + ni * 16 + l16] = f2b(o[mi][ni][r] * inv);
      }
    }
  }
}

// ---------------------------------------------------------------------------
// GEMM2: out(f32) = ctx(bf16 row-major) @ wo^T + wo_b
// ---------------------------------------------------------------------------
__global__ __launch_bounds__(256)
void gemm_ctx(const unsigned short* __restrict__ A,
              const float* __restrict__ Bw,
              const unsigned short* __restrict__ Bbf,
              const float* __restrict__ bias,
              float* __restrict__ C) {
  __shared__ __align__(16) unsigned short As[128 * 64];
  __shared__ __align__(16) unsigned short Bs[128 * 64];
  const int tid  = threadIdx.x;
  const int wave = tid >> 6, lane = tid & 63;
  const int quad = lane >> 4, l16 = lane & 15;
  const int wm = (wave & 1) * 64, wn = (wave >> 1) * 64;
  const int row0A = blockIdx.x * 128;
  const int row0B = blockIdx.y * 128;

  frag_cd acc[4][4];
#pragma unroll
  for (int i = 0; i < 4; i++)
#pragma unroll
    for (int j = 0; j < 4; j++) acc[i][j] = (frag_cd){0.f, 0.f, 0.f, 0.f};

  for (int k0 = 0; k0 < 2048; k0 += 64) {
    stage_a_async(A, As, row0A, k0, wave, lane, 2048);
    if (Bbf) stage_a_async(Bbf, Bs, row0B, k0, wave, lane, 2048);
    else     stage_b_cvt(Bw, Bs, row0B, k0, tid);
    __syncthreads();
#pragma unroll
    for (int kk = 0; kk < 64; kk += 32) {
      frag_ab af[4], bf[4];
#pragma unroll
      for (int mi = 0; mi < 4; mi++) {
        int row = wm + mi * 16 + l16;
        af[mi] = *(const frag_ab*)&As[row * 64 + (((quad + (kk >> 3)) ^ (l16 & 7)) * 8)];
      }
#pragma unroll
      for (int ni = 0; ni < 4; ni++) {
        int row = wn + ni * 16 + l16;
        bf[ni] = *(const frag_ab*)&Bs[row * 64 + (((quad + (kk >> 3)) ^ (l16 & 7)) * 8)];
      }
#pragma unroll
      for (int mi = 0; mi < 4; mi++)
#pragma unroll
        for (int ni = 0; ni < 4; ni++)
          acc[mi][ni] = __builtin_amdgcn_mfma_f32_16x16x32_bf16(af[mi], bf[ni], acc[mi][ni], 0, 0, 0);
    }
    __syncthreads();
  }
#pragma unroll
  for (int ni = 0; ni < 4; ni++) {
    int col = row0B + wn + ni * 16 + l16;
    float bv = bias[col];
#pragma unroll
    for (int mi = 0; mi < 4; mi++) {
#pragma unroll
      for (int r = 0; r < 4; r++) {
        int row = row0A + wm + mi * 16 + quad * 4 + r;
        C[(long)row * 2048 + col] = acc[mi][ni][r] + bv;
      }
    }
  }
}

// ---------------------------------------------------------------------------
extern "C" void kernel_launch(void* const* d_in, const int* in_sizes, int n_in,
                              void* d_out, int out_size, void* d_ws, size_t ws_size,
                              hipStream_t stream) {
  const float* x      = (const float*)d_in[0];
  const float* wqkv_w = (const float*)d_in[1];
  const float* wqkv_b = (const float*)d_in[2];
  const float* wo_w   = (const float*)d_in[3];
  const float* wo_b   = (const float*)d_in[4];

  unsigned short* xb  = (unsigned short*)d_out;              // [0,32MiB)
  unsigned short* Qb  = (unsigned short*)d_out + 16777216;   // [32,64MiB)
  unsigned short* Kb  = (unsigned short*)d_ws;               // ws [0,32MiB)
  unsigned short* Vt  = (unsigned short*)d_ws + 16777216;    // ws [32,64MiB)
  unsigned short* ctx = (unsigned short*)d_out;              // over xb (dead)
  float2* tab = (float2*)d_out;                              // over xb (dead after gemm1)
  float* outf = (float*)d_ws;                                // ws [0,64MiB)

  const bool big = ws_size >= 100663296UL;  // 96 MiB: room for bf16 weights
  unsigned short* Wq = big ? (unsigned short*)d_ws + 33554432 : nullptr; // [64,88MiB)
  unsigned short* Wo = big ? (unsigned short*)d_ws + 46137344 : nullptr; // [88,96MiB)

  // 0) conversions
  cvt_f32_bf16<<<8192, 256, 0, stream>>>(x, xb);
  if (big) {
    cvt_f32_bf16<<<6144, 256, 0, stream>>>(wqkv_w, Wq);
    cvt_f32_bf16<<<2048, 256, 0, stream>>>(wo_w, Wo);
  }
  // 1) QKV projection -> Q,K (bhsd), V^T (bhds)
  gemm_qkv<<<dim3(64, 48), 256, 0, stream>>>(xb, wqkv_w, Wq, wqkv_b, Qb, Kb, Vt);
  // 2) rope table (into dead xb region), then rope in place
  rope_tab<<<512, 256, 0, stream>>>(tab);
  rope_inplace<<<65536, 256, 0, stream>>>(Qb, Kb, tab);
  // 3) flash attention, paired q-tiles, swapped QK^T, dbuf K/V -> ctx
  attn_fwd<<<dim3(64, 8), 256, 0, stream>>>(Qb, Kb, Vt, ctx);
  // 4) output projection -> f32 ws, copy back
  gemm_ctx<<<dim3(64, 16), 256, 0, stream>>>(ctx, wo_w, Wo, wo_b, outf);
  hipMemcpyAsync(d_out, outf, 67108864UL, hipMemcpyDeviceToDevice, stream);
}

// Round 7
// 705.856 us; speedup vs baseline: 1.1048x; 1.0091x over previous
//
#include <hip/hip_runtime.h>

// B=4, S=2048, E=2048, H=16, D=128, full-head rope. f32 I/O, bf16 MFMA inside.
// Memory plan:
//   d_out: xb [0,32MiB) -> rope table (1MiB, xb dead) -> ctx; Qb [32,64MiB)
//   ws:    Kb [0,32), Vt [32,64), optional Wq_bf [64,88), Wo_bf [88,96)
//   GEMM2 -> f32 ws[0,64MiB), D2D copy to d_out.
// LDS tiles staged by global_load_lds are XOR-swizzled (chunk ^= row&7).
// r9: attn paired q-tiles + async V + setprio. r11: swapped QK^T attn.
// r13: attn K/V LDS dbuf (issue-early/drain-at-barrier) + rope cos/sin table
// -> 712.3 us. r10/r12 (8-phase GEMM) FAILED twice -> lane closed, 128^2 kept.
// r14: XCD/L2-locality block remap for both GEMMs. HW linear block id L
// round-robins XCDs (L%8). gemm_qkv FETCH was ~295MB vs 56MB ideal (5x
// refetch; L2 thrash -> 900cy HBM latency inside the per-K-step vmcnt(0)
// drain). Remap gives XCD k contiguous x-groups of 4 A-row-blocks iterated
// over all y: per-XCD working set = A 2MB + B ~2MB = L2-sized. Bijective:
// k=L&7, i=L>>3, g=k+8*(i/(4*GY)), j=i%(4*GY), x=4g+(j&3), y=j>>2.

using frag_ab = __attribute__((ext_vector_type(8))) short;   // 8 bf16 = 4 VGPRs
using frag_cd = __attribute__((ext_vector_type(4))) float;   // 4 f32 acc
typedef __attribute__((ext_vector_type(2))) unsigned int uint2v;

__device__ __forceinline__ float b2f(unsigned short u) {
  union { unsigned int i; float f; } v; v.i = ((unsigned int)u) << 16; return v.f;
}
__device__ __forceinline__ unsigned short f2b(float f) {
  union { float f; unsigned int i; } v; v.f = f;
  unsigned int r = v.i + 0x7FFFu + ((v.i >> 16) & 1u);   // RNE
  return (unsigned short)(r >> 16);
}
__device__ __forceinline__ unsigned int pack2(float a, float b) {
  return (unsigned int)f2b(a) | ((unsigned int)f2b(b) << 16);
}
__device__ __forceinline__ void gload16(const unsigned short* g, unsigned short* l) {
  __builtin_amdgcn_global_load_lds(
      (const __attribute__((address_space(1))) unsigned int*)g,
      (__attribute__((address_space(3))) unsigned int*)l, 16, 0, 0);
}

// XCD-locality remap (gridDim.x must be 64). Bijective on [0, 64*GY).
__device__ __forceinline__ void remap_xy(int GY, int& x, int& y) {
  int L = blockIdx.x + (blockIdx.y << 6);
  int k = L & 7, i = L >> 3;
  int pg = GY << 2;                 // blocks per x-group of 4
  int q = i / pg;
  int j = i - q * pg;
  x = ((k + 8 * q) << 2) + (j & 3);
  y = j >> 2;
}

// ---------------------------------------------------------------------------
__global__ __launch_bounds__(256)
void cvt_f32_bf16(const float* __restrict__ in, unsigned short* __restrict__ out) {
  long i = (long)(blockIdx.x * 256 + threadIdx.x) * 8;
  float4 a = *(const float4*)&in[i];
  float4 b = *(const float4*)&in[i + 4];
  uint4 p;
  p.x = pack2(a.x, a.y); p.y = pack2(a.z, a.w);
  p.z = pack2(b.x, b.y); p.w = pack2(b.z, b.w);
  *(uint4*)&out[i] = p;
}

// ---------------------------------------------------------------------------
// Shared GEMM staging (128x64 bf16 tile, XOR-swizzled chunks).
// ---------------------------------------------------------------------------
__device__ __forceinline__ void stage_a_async(const unsigned short* A, unsigned short* As,
                                              int row0, int k0, int wave, int lane, int ldk) {
#pragma unroll
  for (int i = 0; i < 4; i++) {
    int rbase = wave * 32 + i * 8;
    int r = rbase + (lane >> 3);
    int srcc = (lane & 7) ^ (r & 7);
    gload16(&A[(long)(row0 + r) * ldk + k0 + srcc * 8], &As[rbase * 64]);
  }
}
__device__ __forceinline__ void stage_b_cvt(const float* Bw, unsigned short* Bs,
                                            int row0, int k0, int tid) {
#pragma unroll
  for (int i = 0; i < 4; i++) {
    int c = tid + i * 256;                 // chunk id in [0,1024)
    int r = c >> 3, ch = c & 7;
    const float* src = &Bw[(long)(row0 + r) * 2048 + k0 + ch * 8];
    float4 v0 = *(const float4*)src;
    float4 v1 = *(const float4*)(src + 4);
    uint4 p;
    p.x = pack2(v0.x, v0.y); p.y = pack2(v0.z, v0.w);
    p.z = pack2(v1.x, v1.y); p.w = pack2(v1.z, v1.w);
    *(uint4*)&Bs[r * 64 + ((ch ^ (r & 7)) * 8)] = p;
  }
}

// ---------------------------------------------------------------------------
// GEMM1: qkv = xb @ W^T + bias -> Q (B,H,S,D), K (B,H,S,D), V^T (B,H,D,S)
// ---------------------------------------------------------------------------
__global__ __launch_bounds__(256)
void gemm_qkv(const unsigned short* __restrict__ A,    // xb (8192,2048) bf16
              const float* __restrict__ Bw,            // wqkv_w f32
              const unsigned short* __restrict__ Bbf,  // wqkv_w bf16 or null
              const float* __restrict__ bias,
              unsigned short* __restrict__ Qb,
              unsigned short* __restrict__ Kb,
              unsigned short* __restrict__ Vt) {
  __shared__ __align__(16) unsigned short As[128 * 64];
  __shared__ __align__(16) unsigned short Bs[128 * 64];
  const int tid  = threadIdx.x;
  const int wave = tid >> 6, lane = tid & 63;
  const int quad = lane >> 4, l16 = lane & 15;
  const int wm = (wave & 1) * 64, wn = (wave >> 1) * 64;
  int bx, by;
  remap_xy(48, bx, by);                    // XCD-locality remap
  const int row0A = bx * 128;
  const int row0B = by * 128;

  frag_cd acc[4][4];
#pragma unroll
  for (int i = 0; i < 4; i++)
#pragma unroll
    for (int j = 0; j < 4; j++) acc[i][j] = (frag_cd){0.f, 0.f, 0.f, 0.f};

  for (int k0 = 0; k0 < 2048; k0 += 64) {
    stage_a_async(A, As, row0A, k0, wave, lane, 2048);
    if (Bbf) stage_a_async(Bbf, Bs, row0B, k0, wave, lane, 2048);
    else     stage_b_cvt(Bw, Bs, row0B, k0, tid);
    __syncthreads();
#pragma unroll
    for (int kk = 0; kk < 64; kk += 32) {
      frag_ab af[4], bf[4];
#pragma unroll
      for (int mi = 0; mi < 4; mi++) {
        int row = wm + mi * 16 + l16;
        af[mi] = *(const frag_ab*)&As[row * 64 + (((quad + (kk >> 3)) ^ (l16 & 7)) * 8)];
      }
#pragma unroll
      for (int ni = 0; ni < 4; ni++) {
        int row = wn + ni * 16 + l16;
        bf[ni] = *(const frag_ab*)&Bs[row * 64 + (((quad + (kk >> 3)) ^ (l16 & 7)) * 8)];
      }
#pragma unroll
      for (int mi = 0; mi < 4; mi++)
#pragma unroll
        for (int ni = 0; ni < 4; ni++)
          acc[mi][ni] = __builtin_amdgcn_mfma_f32_16x16x32_bf16(af[mi], bf[ni], acc[mi][ni], 0, 0, 0);
    }
    __syncthreads();
  }
  // scatter epilogue (C/D layout: col=l16, row=quad*4+r; m89-verified)
#pragma unroll
  for (int ni = 0; ni < 4; ni++) {
    int col  = row0B + wn + ni * 16 + l16;
    int h    = col / 384;
    int rem  = col - h * 384;
    int slot = rem >> 7;
    int d    = rem & 127;
    float bv = bias[col];
#pragma unroll
    for (int mi = 0; mi < 4; mi++) {
#pragma unroll
      for (int r = 0; r < 4; r++) {
        int row = row0A + wm + mi * 16 + quad * 4 + r;
        int b = row >> 11, s = row & 2047;
        unsigned short val = f2b(acc[mi][ni][r] + bv);
        if (slot == 0)      Qb[((long)(b * 16 + h) * 2048 + s) * 128 + d] = val;
        else if (slot == 1) Kb[((long)(b * 16 + h) * 2048 + s) * 128 + d] = val;
        else                Vt[((long)(b * 16 + h) * 128 + d) * 2048 + s] = val;
      }
    }
  }
}

// ---------------------------------------------------------------------------
// rope table: tab[s][j] = (cos, sin) of s * 10000^(-2j/128); 2048x64 float2.
// ---------------------------------------------------------------------------
__global__ __launch_bounds__(256)
void rope_tab(float2* __restrict__ tab) {
  int i = blockIdx.x * 256 + threadIdx.x;   // 131072
  int s = i >> 6, j = i & 63;
  float inv = powf(10000.0f, -(float)(2 * j) / 128.0f);
  float ang = (float)s * inv;
  float sn, cs;
  sincosf(ang, &sn, &cs);
  tab[i] = make_float2(cs, sn);
}

// ---------------------------------------------------------------------------
// rope in place from table; attention scale 1/sqrt(128) folded into Q.
// ---------------------------------------------------------------------------
__global__ __launch_bounds__(256)
void rope_inplace(unsigned short* __restrict__ Qb, unsigned short* __restrict__ Kb,
                  const float2* __restrict__ tab) {
  int wid  = blockIdx.x * 4 + (threadIdx.x >> 6);
  int j    = threadIdx.x & 63;
  int part = wid & 1;
  int s    = (wid >> 1) & 2047;
  int bh   = wid >> 12;
  unsigned short* buf = part ? Kb : Qb;
  long base = ((long)bh * 2048 + s) * 128;
  unsigned int pr = *(const unsigned int*)&buf[base + 2 * j];
  float x1 = b2f((unsigned short)(pr & 0xFFFFu));
  float x2 = b2f((unsigned short)(pr >> 16));
  float2 t = tab[s * 64 + j];
  float sc = part ? 1.0f : 0.08838834764831845f;   // Q pre-scaled for attn
  float cs = t.x * sc, sn = t.y * sc;
  buf[base + j]      = f2b(x1 * cs - x2 * sn);
  buf[base + 64 + j] = f2b(x1 * sn + x2 * cs);
}

// ---------------------------------------------------------------------------
// Causal flash attention (r13-proven). Q,K (B,H,S,D), Q pre-scaled; V^T.
// Paired q-tiles; swapped QK^T; 2-shuffle softmax; b64 P stores; K/V dbuf
// with issue-early/drain-at-barrier (1 barrier per kv tile).
// ---------------------------------------------------------------------------
__device__ __forceinline__ void attn_stage(const unsigned short* __restrict__ K,
                                           const unsigned short* __restrict__ Vt,
                                           long base, long vbase, int kv0,
                                           unsigned short* Kbuf, unsigned short* Vbuf,
                                           int wave, int lane) {
  // K: 64x128, 16-chunk XOR swizzle
#pragma unroll
  for (int i = 0; i < 4; i++) {
    int rbase = (wave * 4 + i) * 4;
    int r = rbase + (lane >> 4);
    int srcc = (lane & 15) ^ (r & 15);
    gload16(&K[base + (long)(kv0 + r) * 128 + srcc * 8], &Kbuf[rbase * 128]);
  }
  // V^T: 128x64, 8-chunk XOR swizzle
#pragma unroll
  for (int i = 0; i < 4; i++) {
    int rbase = wave * 32 + i * 8;
    int r = rbase + (lane >> 3);
    int srcc = (lane & 7) ^ (r & 7);
    gload16(&Vt[vbase + (long)r * 2048 + kv0 + srcc * 8], &Vbuf[rbase * 64]);
  }
}

__global__ __launch_bounds__(256)
void attn_fwd(const unsigned short* __restrict__ Q,
              const unsigned short* __restrict__ K,
              const unsigned short* __restrict__ Vt,
              unsigned short* __restrict__ ctx) {
  __shared__ __align__(16) unsigned short Ks[2][64 * 128];  // 32 KB
  __shared__ __align__(16) unsigned short Vs[2][128 * 64];  // 32 KB
  __shared__ __align__(16) unsigned short Ps[4][32 * 64];   // 16 KB, per-wave
  const int bh = blockIdx.x;
  const int tid = threadIdx.x;
  const int wave = tid >> 6, lane = tid & 63;
  const int quad = lane >> 4, l16 = lane & 15;
  const long base  = (long)bh * 2048 * 128;
  const long vbase = (long)bh * 262144;
  const int b = bh >> 4, h = bh & 15;
  unsigned short* pw = &Ps[wave][0];

  for (int pass = 0; pass < 2; ++pass) {
    const int qt = pass ? (15 - blockIdx.y) : blockIdx.y;
    const int q0 = qt * 128 + wave * 32;

    frag_ab qf[2][4];
#pragma unroll
    for (int mi = 0; mi < 2; mi++)
#pragma unroll
      for (int ks = 0; ks < 4; ks++)
        qf[mi][ks] = *(const frag_ab*)&Q[base + (long)(q0 + mi * 16 + l16) * 128 + ks * 32 + quad * 8];

    frag_cd o[2][8];
#pragma unroll
    for (int mi = 0; mi < 2; mi++)
#pragma unroll
      for (int ni = 0; ni < 8; ni++) o[mi][ni] = (frag_cd){0.f, 0.f, 0.f, 0.f};
    float m_i[2] = {-1.0e30f, -1.0e30f};   // stats for q = l16 (dup across quads)
    float l_i[2] = {0.f, 0.f};

    const int nt = qt * 2 + 2;             // kv tiles (even)
    attn_stage(K, Vt, base, vbase, 0, Ks[0], Vs[0], wave, lane);
    __syncthreads();

    for (int t = 0; t < nt; ++t) {
      const int kv0 = t * 64;
      const int c = t & 1;
      if (t + 1 < nt)                      // issue next tile NOW (overlaps compute)
        attn_stage(K, Vt, base, vbase, kv0 + 64, Ks[c ^ 1], Vs[c ^ 1], wave, lane);

      if (kv0 <= q0 + 31) {                // else: fully masked for this wave
        const unsigned short* ks_ = Ks[c];
        const unsigned short* vs_ = Vs[c];
        // S^T = K @ Q^T : p[mi][kt][r] = S[q=l16][kv=kt*16+quad*4+r]
        float p[2][4][4];
        __builtin_amdgcn_s_setprio(1);
#pragma unroll
        for (int kt = 0; kt < 4; kt++) {
          frag_ab kf[4];
          int row = kt * 16 + l16;
#pragma unroll
          for (int ks = 0; ks < 4; ks++)
            kf[ks] = *(const frag_ab*)&ks_[row * 128 + (((ks * 4 + quad) ^ (row & 15)) * 8)];
#pragma unroll
          for (int mi = 0; mi < 2; mi++) {
            frag_cd acc = (frag_cd){0.f, 0.f, 0.f, 0.f};
#pragma unroll
            for (int ks = 0; ks < 4; ks++)
              acc = __builtin_amdgcn_mfma_f32_16x16x32_bf16(kf[ks], qf[mi][ks], acc, 0, 0, 0);
#pragma unroll
            for (int r = 0; r < 4; r++) p[mi][kt][r] = acc[r];
          }
        }
        __builtin_amdgcn_s_setprio(0);

        if (kv0 + 63 > q0) {               // diagonal tiles: apply causal mask
#pragma unroll
          for (int mi = 0; mi < 2; mi++) {
            int qg = q0 + mi * 16 + l16;
#pragma unroll
            for (int kt = 0; kt < 4; kt++)
#pragma unroll
              for (int r = 0; r < 4; r++) {
                int kvg = kv0 + kt * 16 + quad * 4 + r;
                if (kvg > qg) p[mi][kt][r] = -10000.0f;
              }
          }
        }

        // online softmax: stats per q=l16, replicated across quads
        float alpha[2];
#pragma unroll
        for (int mi = 0; mi < 2; mi++) {
          float mx = -1.0e30f;
#pragma unroll
          for (int kt = 0; kt < 4; kt++)
            mx = fmaxf(mx, fmaxf(fmaxf(p[mi][kt][0], p[mi][kt][1]),
                                 fmaxf(p[mi][kt][2], p[mi][kt][3])));
          mx = fmaxf(mx, __shfl_xor(mx, 16, 64));
          mx = fmaxf(mx, __shfl_xor(mx, 32, 64));
          float mnew = fmaxf(m_i[mi], mx);
          alpha[mi] = __expf(m_i[mi] - mnew);
          m_i[mi] = mnew;
          float rs = 0.f;
#pragma unroll
          for (int kt = 0; kt < 4; kt++)
#pragma unroll
            for (int r = 0; r < 4; r++) {
              float e = __expf(p[mi][kt][r] - mnew);
              p[mi][kt][r] = e;
              rs += e;
            }
          rs += __shfl_xor(rs, 16, 64);
          rs += __shfl_xor(rs, 32, 64);
          l_i[mi] = l_i[mi] * alpha[mi] + rs;
        }

        // rescale O (alpha at q=l16 lanes; o rows are q=quad*4+r)
        if (!(__all(alpha[0] == 1.0f) && __all(alpha[1] == 1.0f))) {
#pragma unroll
          for (int mi = 0; mi < 2; mi++) {
            float ar[4];
#pragma unroll
            for (int r = 0; r < 4; r++) ar[r] = __shfl(alpha[mi], quad * 4 + r, 64);
#pragma unroll
            for (int ni = 0; ni < 8; ni++)
#pragma unroll
              for (int r = 0; r < 4; r++) o[mi][ni][r] *= ar[r];
          }
        }

        // P -> LDS: b64 packed, chunk-XOR swizzle (row = mi*16+l16 = q)
#pragma unroll
        for (int mi = 0; mi < 2; mi++) {
          int row = mi * 16 + l16;
#pragma unroll
          for (int kt = 0; kt < 4; kt++) {
            unsigned int u0 = pack2(p[mi][kt][0], p[mi][kt][1]);
            unsigned int u1 = pack2(p[mi][kt][2], p[mi][kt][3]);
            int ch = kt * 2 + (quad >> 1);
            int addr = row * 64 + ((ch ^ (l16 & 7)) * 8) + (quad & 1) * 4;
            *(uint2v*)&pw[addr] = (uint2v){u0, u1};
          }
        }

        // O += P @ V  (pf: A-operand rows q=l16; vf: B-operand rows d=l16)
        frag_ab pf[2][2];
#pragma unroll
        for (int mi = 0; mi < 2; mi++)
#pragma unroll
          for (int ks = 0; ks < 2; ks++)
            pf[mi][ks] = *(const frag_ab*)&pw[(mi * 16 + l16) * 64 +
                                              (((ks * 4 + quad) ^ (l16 & 7)) * 8)];
        __builtin_amdgcn_s_setprio(1);
#pragma unroll
        for (int ni = 0; ni < 8; ni++) {
          int vrow = ni * 16 + l16;
          frag_ab vf0 = *(const frag_ab*)&vs_[vrow * 64 + ((quad ^ (l16 & 7)) * 8)];
          frag_ab vf1 = *(const frag_ab*)&vs_[vrow * 64 + (((quad + 4) ^ (l16 & 7)) * 8)];
#pragma unroll
          for (int mi = 0; mi < 2; mi++) {
            o[mi][ni] = __builtin_amdgcn_mfma_f32_16x16x32_bf16(pf[mi][0], vf0, o[mi][ni], 0, 0, 0);
            o[mi][ni] = __builtin_amdgcn_mfma_f32_16x16x32_bf16(pf[mi][1], vf1, o[mi][ni], 0, 0, 0);
          }
        }
        __builtin_amdgcn_s_setprio(0);
      }
      __syncthreads();                     // drains next-tile loads + barrier
    }

    // ctx row-major (B,S,E); 1/l broadcast from q=l16 lanes to o-rows
#pragma unroll
    for (int mi = 0; mi < 2; mi++) {
      float rl = 1.0f / fmaxf(l_i[mi], 1.0e-20f);
#pragma unroll
      for (int r = 0; r < 4; r++) {
        float inv = __shfl(rl, quad * 4 + r, 64);
        int s = q0 + mi * 16 + quad * 4 + r;
        long rowb = ((long)b * 2048 + s) * 2048 + h * 128;
#pragma unroll
        for (int ni = 0; ni < 8; ni++)
          ctx[rowb + ni * 16 + l16] = f2b(o[mi][ni][r] * inv);
      }
    }
  }
}

// ---------------------------------------------------------------------------
// GEMM2: out(f32) = ctx(bf16 row-major) @ wo^T + wo_b
// ---------------------------------------------------------------------------
__global__ __launch_bounds__(256)
void gemm_ctx(const unsigned short* __restrict__ A,
              const float* __restrict__ Bw,
              const unsigned short* __restrict__ Bbf,
              const float* __restrict__ bias,
              float* __restrict__ C) {
  __shared__ __align__(16) unsigned short As[128 * 64];
  __shared__ __align__(16) unsigned short Bs[128 * 64];
  const int tid  = threadIdx.x;
  const int wave = tid >> 6, lane = tid & 63;
  const int quad = lane >> 4, l16 = lane & 15;
  const int wm = (wave & 1) * 64, wn = (wave >> 1) * 64;
  int bx, by;
  remap_xy(16, bx, by);                    // XCD-locality remap
  const int row0A = bx * 128;
  const int row0B = by * 128;

  frag_cd acc[4][4];
#pragma unroll
  for (int i = 0; i < 4; i++)
#pragma unroll
    for (int j = 0; j < 4; j++) acc[i][j] = (frag_cd){0.f, 0.f, 0.f, 0.f};

  for (int k0 = 0; k0 < 2048; k0 += 64) {
    stage_a_async(A, As, row0A, k0, wave, lane, 2048);
    if (Bbf) stage_a_async(Bbf, Bs, row0B, k0, wave, lane, 2048);
    else     stage_b_cvt(Bw, Bs, row0B, k0, tid);
    __syncthreads();
#pragma unroll
    for (int kk = 0; kk < 64; kk += 32) {
      frag_ab af[4], bf[4];
#pragma unroll
      for (int mi = 0; mi < 4; mi++) {
        int row = wm + mi * 16 + l16;
        af[mi] = *(const frag_ab*)&As[row * 64 + (((quad + (kk >> 3)) ^ (l16 & 7)) * 8)];
      }
#pragma unroll
      for (int ni = 0; ni < 4; ni++) {
        int row = wn + ni * 16 + l16;
        bf[ni] = *(const frag_ab*)&Bs[row * 64 + (((quad + (kk >> 3)) ^ (l16 & 7)) * 8)];
      }
#pragma unroll
      for (int mi = 0; mi < 4; mi++)
#pragma unroll
        for (int ni = 0; ni < 4; ni++)
          acc[mi][ni] = __builtin_amdgcn_mfma_f32_16x16x32_bf16(af[mi], bf[ni], acc[mi][ni], 0, 0, 0);
    }
    __syncthreads();
  }
#pragma unroll
  for (int ni = 0; ni < 4; ni++) {
    int col = row0B + wn + ni * 16 + l16;
    float bv = bias[col];
#pragma unroll
    for (int mi = 0; mi < 4; mi++) {
#pragma unroll
      for (int r = 0; r < 4; r++) {
        int row = row0A + wm + mi * 16 + quad * 4 + r;
        C[(long)row * 2048 + col] = acc[mi][ni][r] + bv;
      }
    }
  }
}

// ---------------------------------------------------------------------------
extern "C" void kernel_launch(void* const* d_in, const int* in_sizes, int n_in,
                              void* d_out, int out_size, void* d_ws, size_t ws_size,
                              hipStream_t stream) {
  const float* x      = (const float*)d_in[0];
  const float* wqkv_w = (const float*)d_in[1];
  const float* wqkv_b = (const float*)d_in[2];
  const float* wo_w   = (const float*)d_in[3];
  const float* wo_b   = (const float*)d_in[4];

  unsigned short* xb  = (unsigned short*)d_out;              // [0,32MiB)
  unsigned short* Qb  = (unsigned short*)d_out + 16777216;   // [32,64MiB)
  unsigned short* Kb  = (unsigned short*)d_ws;               // ws [0,32MiB)
  unsigned short* Vt  = (unsigned short*)d_ws + 16777216;    // ws [32,64MiB)
  unsigned short* ctx = (unsigned short*)d_out;              // over xb (dead)
  float2* tab = (float2*)d_out;                              // over xb (dead after gemm1)
  float* outf = (float*)d_ws;                                // ws [0,64MiB)

  const bool big = ws_size >= 100663296UL;  // 96 MiB: room for bf16 weights
  unsigned short* Wq = big ? (unsigned short*)d_ws + 33554432 : nullptr; // [64,88MiB)
  unsigned short* Wo = big ? (unsigned short*)d_ws + 46137344 : nullptr; // [88,96MiB)

  // 0) conversions
  cvt_f32_bf16<<<8192, 256, 0, stream>>>(x, xb);
  if (big) {
    cvt_f32_bf16<<<6144, 256, 0, stream>>>(wqkv_w, Wq);
    cvt_f32_bf16<<<2048, 256, 0, stream>>>(wo_w, Wo);
  }
  // 1) QKV projection -> Q,K (bhsd), V^T (bhds)
  gemm_qkv<<<dim3(64, 48), 256, 0, stream>>>(xb, wqkv_w, Wq, wqkv_b, Qb, Kb, Vt);
  // 2) rope table (into dead xb region), then rope in place
  rope_tab<<<512, 256, 0, stream>>>(tab);
  rope_inplace<<<65536, 256, 0, stream>>>(Qb, Kb, tab);
  // 3) flash attention, paired q-tiles, swapped QK^T, dbuf K/V -> ctx
  attn_fwd<<<dim3(64, 8), 256, 0, stream>>>(Qb, Kb, Vt, ctx);
  // 4) output projection -> f32 ws, copy back
  gemm_ctx<<<dim3(64, 16), 256, 0, stream>>>(ctx, wo_w, Wo, wo_b, outf);
  hipMemcpyAsync(d_out, outf, 67108864UL, hipMemcpyDeviceToDevice, stream);
}